// Round 5
// baseline (793.276 us; speedup 1.0000x reference)
//
#include <hip/hip_runtime.h>

typedef __bf16 bf16_t;
typedef bf16_t bf16x8 __attribute__((ext_vector_type(8)));
typedef bf16_t bf16x4 __attribute__((ext_vector_type(4)));
typedef float f32x4 __attribute__((ext_vector_type(4)));

#define MFMA(a, b, c) __builtin_amdgcn_mfma_f32_16x16x32_bf16((a), (b), (c), 0, 0, 0)

// ---------------- f32 -> bf16 convert (vectorized, 8 elems/thread) ----------------
__global__ __launch_bounds__(256) void k_cvt_bf16(const float* __restrict__ in,
                                                  bf16_t* __restrict__ out, long n) {
  long i = ((long)blockIdx.x * 256 + threadIdx.x) * 8;
  if (i >= n) return;
  float4 a = *(const float4*)(in + i);
  float4 b = *(const float4*)(in + i + 4);
  bf16x8 o;
  o[0] = (bf16_t)a.x; o[1] = (bf16_t)a.y; o[2] = (bf16_t)a.z; o[3] = (bf16_t)a.w;
  o[4] = (bf16_t)b.x; o[5] = (bf16_t)b.y; o[6] = (bf16_t)b.z; o[7] = (bf16_t)b.w;
  *(bf16x8*)(out + i) = o;
}

// ---------------- transpose (K,N) f32 -> (N,K) bf16, 32x32 LDS tiles ----------------
__global__ __launch_bounds__(256) void k_transpose_bf16(const float* __restrict__ in,
                                                        bf16_t* __restrict__ out,
                                                        int K, int N) {
  __shared__ float t[32][33];
  int k0 = blockIdx.x * 32, n0 = blockIdx.y * 32;
  int tx = threadIdx.x & 31, ty = threadIdx.x >> 5;  // 32 x 8
#pragma unroll
  for (int r = 0; r < 4; ++r)
    t[ty + r * 8][tx] = in[(long)(k0 + ty + r * 8) * N + n0 + tx];
  __syncthreads();
#pragma unroll
  for (int r = 0; r < 4; ++r)
    out[(long)(n0 + ty + r * 8) * K + k0 + tx] = (bf16_t)t[tx][ty + r * 8];
}

// ---------------- GEMM: C[M,N] = A[M,K] * Bt[N,K]^T  (bf16 MFMA, fp32 acc) --------
// 128x128 tile, BK=32, 4 waves each 64x64. Reg-staged LDS with XOR block swizzle.
template <typename OUT_T>
__global__ __launch_bounds__(256) void k_gemm_bt(const bf16_t* __restrict__ A,
                                                 const bf16_t* __restrict__ Bt,
                                                 OUT_T* __restrict__ C,
                                                 int M, int N, int K) {
  __shared__ bf16_t Al[128 * 32];
  __shared__ bf16_t Bl[128 * 32];
  int tid = threadIdx.x;
  int lane = tid & 63, w = tid >> 6;
  int l16 = lane & 15, lg = lane >> 4;
  int m0 = blockIdx.x * 128, n0 = blockIdx.y * 128;
  int wm = (w >> 1) * 64, wn = (w & 1) * 64;

  // staging chunk mapping: 512 chunks of 16B; LDS slot (row, bb) holds data block bb^((row>>1)&3)
  int c0 = tid, c1 = tid + 256;
  int r0 = c0 >> 2, bb0 = c0 & 3;
  int r1 = c1 >> 2, bb1 = c1 & 3;
  int g0 = bb0 ^ ((r0 >> 1) & 3);
  int g1 = bb1 ^ ((r1 >> 1) & 3);

  f32x4 acc[4][4] = {};

  const bf16_t* Ar0 = A + (long)(m0 + r0) * K + g0 * 8;
  const bf16_t* Ar1 = A + (long)(m0 + r1) * K + g1 * 8;
  const bf16_t* Br0 = Bt + (long)(n0 + r0) * K + g0 * 8;
  const bf16_t* Br1 = Bt + (long)(n0 + r1) * K + g1 * 8;

  for (int k0 = 0; k0 < K; k0 += 32) {
    bf16x8 av0 = *(const bf16x8*)(Ar0 + k0);
    bf16x8 av1 = *(const bf16x8*)(Ar1 + k0);
    bf16x8 bv0 = *(const bf16x8*)(Br0 + k0);
    bf16x8 bv1 = *(const bf16x8*)(Br1 + k0);
    __syncthreads();  // previous iter's ds_reads complete
    *(bf16x8*)(Al + r0 * 32 + bb0 * 8) = av0;
    *(bf16x8*)(Al + r1 * 32 + bb1 * 8) = av1;
    *(bf16x8*)(Bl + r0 * 32 + bb0 * 8) = bv0;
    *(bf16x8*)(Bl + r1 * 32 + bb1 * 8) = bv1;
    __syncthreads();
    bf16x8 af[4], bfr[4];
#pragma unroll
    for (int mf = 0; mf < 4; ++mf) {
      int row = wm + mf * 16 + l16;
      af[mf] = *(const bf16x8*)(Al + row * 32 + ((lg ^ ((row >> 1) & 3)) * 8));
    }
#pragma unroll
    for (int nf = 0; nf < 4; ++nf) {
      int row = wn + nf * 16 + l16;
      bfr[nf] = *(const bf16x8*)(Bl + row * 32 + ((lg ^ ((row >> 1) & 3)) * 8));
    }
#pragma unroll
    for (int mf = 0; mf < 4; ++mf)
#pragma unroll
      for (int nf = 0; nf < 4; ++nf)
        acc[mf][nf] = MFMA(af[mf], bfr[nf], acc[mf][nf]);
  }

#pragma unroll
  for (int mf = 0; mf < 4; ++mf)
#pragma unroll
    for (int nf = 0; nf < 4; ++nf)
#pragma unroll
      for (int r = 0; r < 4; ++r) {
        int row = m0 + wm + mf * 16 + lg * 4 + r;
        int col = n0 + wn + nf * 16 + l16;
        C[(long)row * N + col] = (OUT_T)acc[mf][nf][r];
      }
}

// ---------------- fused LayerNorm (+optional RoPE), fp32 in -> bf16 out -----------
// LN over the full row of C (2048 for q, 512 for k/ky), then RoPE per 64-elem head.
template <int C, bool ROPE>
__global__ __launch_bounds__(256) void k_ln_rope(const float* __restrict__ in,
                                                 const float* __restrict__ gw,
                                                 const float* __restrict__ gb,
                                                 const float* __restrict__ fc,
                                                 const float* __restrict__ fs,
                                                 bf16_t* __restrict__ out, int smask) {
  int row = blockIdx.x;
  int tid = threadIdx.x;
  const float* x = in + (long)row * C;
  float s = 0.f, ss = 0.f;
  for (int i = tid * 4; i < C; i += 1024) {
    float4 v = *(const float4*)(x + i);
    s += v.x + v.y + v.z + v.w;
    ss += v.x * v.x + v.y * v.y + v.z * v.z + v.w * v.w;
  }
#pragma unroll
  for (int msk = 1; msk < 64; msk <<= 1) {
    s += __shfl_xor(s, msk);
    ss += __shfl_xor(ss, msk);
  }
  __shared__ float rs[2][4];
  int w = tid >> 6, lane = tid & 63;
  if (lane == 0) { rs[0][w] = s; rs[1][w] = ss; }
  __syncthreads();
  s = rs[0][0] + rs[0][1] + rs[0][2] + rs[0][3];
  ss = rs[1][0] + rs[1][1] + rs[1][2] + rs[1][3];
  float mean = s * (1.0f / (float)C);
  float inv = rsqrtf(ss * (1.0f / (float)C) - mean * mean + 1e-5f);
  int srow = row & smask;
  for (int i = tid * 4; i < C; i += 1024) {
    float4 v = *(const float4*)(x + i);
    float n0 = (v.x - mean) * inv * gw[i + 0] + gb[i + 0];
    float n1 = (v.y - mean) * inv * gw[i + 1] + gb[i + 1];
    float n2 = (v.z - mean) * inv * gw[i + 2] + gb[i + 2];
    float n3 = (v.w - mean) * inv * gw[i + 3] + gb[i + 3];
    bf16x4 o;
    if (ROPE) {
      int dh = i & 63;               // i is a multiple of 4 -> dh in {0,4,...,60}
      int f0 = dh >> 1, f1 = f0 + 1; // freq indices for the two pairs
      float c0 = fc[srow * 32 + f0], s0 = fs[srow * 32 + f0];
      float c1 = fc[srow * 32 + f1], s1 = fs[srow * 32 + f1];
      o[0] = (bf16_t)(n0 * c0 - n1 * s0);
      o[1] = (bf16_t)(n0 * s0 + n1 * c0);
      o[2] = (bf16_t)(n2 * c1 - n3 * s1);
      o[3] = (bf16_t)(n2 * s1 + n3 * c1);
    } else {
      o[0] = (bf16_t)n0; o[1] = (bf16_t)n1; o[2] = (bf16_t)n2; o[3] = (bf16_t)n3;
    }
    *(bf16x4*)(out + (long)row * C + i) = o;
  }
}

// ---------------- fused GQA attention: self (S keys) + gated cross (YL keys) -------
// grid (S/64, NH, B), 256 thr. Wave w owns 16 q-rows. Flash online softmax.
__global__ __launch_bounds__(256) void k_attn(const bf16_t* __restrict__ Q,
                                              const bf16_t* __restrict__ Kx,
                                              const bf16_t* __restrict__ Vx,
                                              const bf16_t* __restrict__ Ky,
                                              const bf16_t* __restrict__ Vy,
                                              const float* __restrict__ gate,
                                              bf16_t* __restrict__ out, int S, int YL) {
  __shared__ bf16_t Kl[64 * 72];     // [key][d] padded to 72 (144B rows, bank-clean)
  __shared__ bf16_t Vt[64 * 72];     // [d][key] padded
  __shared__ bf16_t Pl[4][16 * 72];  // per-wave P tile [qrow][key] padded

  int tid = threadIdx.x;
  int lane = tid & 63, w = tid >> 6;
  int l16 = lane & 15, lg = lane >> 4;
  int qt = blockIdx.x, h = blockIdx.y, b = blockIdx.z;
  int kv = h >> 2;  // n_rep = NH/NKV = 4

  bf16x8 qf[2];
  {
    long qoff = ((long)(b * S + qt * 64 + w * 16 + l16)) * 2048 + h * 64;
    qf[0] = *(const bf16x8*)(Q + qoff + lg * 8);
    qf[1] = *(const bf16x8*)(Q + qoff + 32 + lg * 8);
  }

  int i0 = tid, i1 = tid + 256;
  int kr0 = i0 >> 3, kb0 = i0 & 7;
  int kr1 = i1 >> 3, kb1 = i1 & 7;

  float res[4][4];
  float tg = tanhf(gate[h]);

  for (int phase = 0; phase < 2; ++phase) {
    const bf16_t* Kg = phase ? (Ky + (long)b * YL * 512 + kv * 64)
                             : (Kx + (long)b * S * 512 + kv * 64);
    const bf16_t* Vg = phase ? (Vy + (long)b * YL * 512 + kv * 64)
                             : (Vx + (long)b * S * 512 + kv * 64);
    int nt = (phase ? YL : S) >> 6;

    float mr[4], lr[4];
    f32x4 o[4] = {};
#pragma unroll
    for (int r = 0; r < 4; ++r) { mr[r] = -1e30f; lr[r] = 0.f; }

    for (int t = 0; t < nt; ++t) {
      const bf16_t* kt = Kg + (long)t * 64 * 512;
      const bf16_t* vt = Vg + (long)t * 64 * 512;
      bf16x8 kc0 = *(const bf16x8*)(kt + kr0 * 512 + kb0 * 8);
      bf16x8 kc1 = *(const bf16x8*)(kt + kr1 * 512 + kb1 * 8);
      bf16x8 vc0 = *(const bf16x8*)(vt + kr0 * 512 + kb0 * 8);
      bf16x8 vc1 = *(const bf16x8*)(vt + kr1 * 512 + kb1 * 8);
      __syncthreads();  // prior tile's LDS reads done
      *(bf16x8*)(Kl + kr0 * 72 + kb0 * 8) = kc0;
      *(bf16x8*)(Kl + kr1 * 72 + kb1 * 8) = kc1;
#pragma unroll
      for (int j = 0; j < 8; ++j) {  // V transposed scatter
        Vt[(kb0 * 8 + j) * 72 + kr0] = vc0[j];
        Vt[(kb1 * 8 + j) * 72 + kr1] = vc1[j];
      }
      __syncthreads();

      // scores S[q][key] = Q . K^T (scaled)
      f32x4 sc[4] = {};
#pragma unroll
      for (int kf = 0; kf < 2; ++kf)
#pragma unroll
        for (int nf = 0; nf < 4; ++nf) {
          bf16x8 kfr = *(const bf16x8*)(Kl + (nf * 16 + l16) * 72 + kf * 32 + lg * 8);
          sc[nf] = MFMA(qf[kf], kfr, sc[nf]);
        }
      float tmax[4], tsum[4], al[4];
#pragma unroll
      for (int nf = 0; nf < 4; ++nf) sc[nf] *= 0.125f;  // 1/sqrt(64)
#pragma unroll
      for (int r = 0; r < 4; ++r) {
        tmax[r] = fmaxf(fmaxf(sc[0][r], sc[1][r]), fmaxf(sc[2][r], sc[3][r]));
#pragma unroll
        for (int msk = 1; msk < 16; msk <<= 1)
          tmax[r] = fmaxf(tmax[r], __shfl_xor(tmax[r], msk));
        float mn = fmaxf(mr[r], tmax[r]);
        al[r] = __expf(mr[r] - mn);
        mr[r] = mn;
        tsum[r] = 0.f;
      }
#pragma unroll
      for (int nf = 0; nf < 4; ++nf)
#pragma unroll
        for (int r = 0; r < 4; ++r) {
          float p = __expf(sc[nf][r] - mr[r]);
          sc[nf][r] = p;
          tsum[r] += p;
        }
#pragma unroll
      for (int r = 0; r < 4; ++r) {
#pragma unroll
        for (int msk = 1; msk < 16; msk <<= 1) tsum[r] += __shfl_xor(tsum[r], msk);
        lr[r] = lr[r] * al[r] + tsum[r];
      }
#pragma unroll
      for (int df = 0; df < 4; ++df)
#pragma unroll
        for (int r = 0; r < 4; ++r) o[df][r] *= al[r];
      // P -> LDS (D-layout rows lg*4+r) then re-read in A-layout
#pragma unroll
      for (int nf = 0; nf < 4; ++nf)
#pragma unroll
        for (int r = 0; r < 4; ++r)
          Pl[w][(lg * 4 + r) * 72 + nf * 16 + l16] = (bf16_t)sc[nf][r];
#pragma unroll
      for (int kb = 0; kb < 2; ++kb) {
        bf16x8 pa = *(const bf16x8*)(&Pl[w][l16 * 72 + kb * 32 + lg * 8]);
#pragma unroll
        for (int df = 0; df < 4; ++df) {
          bf16x8 vb = *(const bf16x8*)(Vt + (df * 16 + l16) * 72 + kb * 32 + lg * 8);
          o[df] = MFMA(pa, vb, o[df]);
        }
      }
    }
#pragma unroll
    for (int df = 0; df < 4; ++df)
#pragma unroll
      for (int r = 0; r < 4; ++r) {
        float v = o[df][r] / lr[r];
        if (phase == 0) res[df][r] = v;
        else res[df][r] += tg * v;
      }
  }

  long obase = ((long)(b * S + qt * 64 + w * 16 + lg * 4)) * 2048 + h * 64 + l16;
#pragma unroll
  for (int df = 0; df < 4; ++df)
#pragma unroll
    for (int r = 0; r < 4; ++r)
      out[obase + (long)r * 2048 + df * 16] = (bf16_t)res[df][r];
}

// ------------------------------- launch ------------------------------------------
extern "C" void kernel_launch(void* const* d_in, const int* in_sizes, int n_in,
                              void* d_out, int out_size, void* d_ws, size_t ws_size,
                              hipStream_t stream) {
  const float* x    = (const float*)d_in[0];
  const float* fc   = (const float*)d_in[2];
  const float* fs   = (const float*)d_in[3];
  const float* y    = (const float*)d_in[4];
  const float* wq   = (const float*)d_in[6];
  const float* wk   = (const float*)d_in[7];
  const float* wv   = (const float*)d_in[8];
  const float* wky  = (const float*)d_in[9];
  const float* wvy  = (const float*)d_in[10];
  const float* wo   = (const float*)d_in[11];
  const float* gate = (const float*)d_in[12];
  const float* qnw  = (const float*)d_in[13];
  const float* qnb  = (const float*)d_in[14];
  const float* knw  = (const float*)d_in[15];
  const float* knb  = (const float*)d_in[16];
  const float* kynw = (const float*)d_in[17];
  const float* kynb = (const float*)d_in[18];
  float* outp = (float*)d_out;

  constexpr int B = 2, S = 2048, D = 2048, NH = 32, YLv = 256, YD = 1024;
  constexpr int MQ = B * S;    // 4096 rows
  constexpr int MY = B * YLv;  // 512 rows
  constexpr int NQK = 2048;    // NH*HD
  constexpr int NKVd = 512;    // NKV*HD

  char* p = (char*)d_ws;
  auto alloc = [&](long bytes) { char* r = p; p += (bytes + 255) & ~255L; return r; };
  float*  tmp  = (float*)alloc((long)MQ * NQK * 4);  // LN scratch; attb aliases it later
  bf16_t* xb   = (bf16_t*)alloc((long)MQ * D * 2);
  bf16_t* yb   = (bf16_t*)alloc((long)MY * YD * 2);
  bf16_t* wqt  = (bf16_t*)alloc((long)NQK * D * 2);
  bf16_t* wkt  = (bf16_t*)alloc((long)NKVd * D * 2);
  bf16_t* wvt  = (bf16_t*)alloc((long)NKVd * D * 2);
  bf16_t* wkyt = (bf16_t*)alloc((long)NKVd * YD * 2);
  bf16_t* wvyt = (bf16_t*)alloc((long)NKVd * YD * 2);
  bf16_t* wot  = (bf16_t*)alloc((long)D * NQK * 2);
  bf16_t* Qb   = (bf16_t*)alloc((long)MQ * NQK * 2);
  bf16_t* Kb   = (bf16_t*)alloc((long)MQ * NKVd * 2);
  bf16_t* Vb   = (bf16_t*)alloc((long)MQ * NKVd * 2);
  bf16_t* yKb  = (bf16_t*)alloc((long)MY * NKVd * 2);
  bf16_t* yVb  = (bf16_t*)alloc((long)MY * NKVd * 2);
  bf16_t* attb = (bf16_t*)tmp;  // overlay: tmp's last read precedes k_attn's write

  // activations -> bf16
  k_cvt_bf16<<<dim3(((long)MQ * D) / 2048), dim3(256), 0, stream>>>(x, xb, (long)MQ * D);
  k_cvt_bf16<<<dim3(((long)MY * YD) / 2048), dim3(256), 0, stream>>>(y, yb, (long)MY * YD);
  // weights -> transposed bf16 (N,K)
  k_transpose_bf16<<<dim3(D / 32, NQK / 32), dim3(256), 0, stream>>>(wq, wqt, D, NQK);
  k_transpose_bf16<<<dim3(D / 32, NKVd / 32), dim3(256), 0, stream>>>(wk, wkt, D, NKVd);
  k_transpose_bf16<<<dim3(D / 32, NKVd / 32), dim3(256), 0, stream>>>(wv, wvt, D, NKVd);
  k_transpose_bf16<<<dim3(YD / 32, NKVd / 32), dim3(256), 0, stream>>>(wky, wkyt, YD, NKVd);
  k_transpose_bf16<<<dim3(YD / 32, NKVd / 32), dim3(256), 0, stream>>>(wvy, wvyt, YD, NKVd);
  k_transpose_bf16<<<dim3(NQK / 32, D / 32), dim3(256), 0, stream>>>(wo, wot, NQK, D);

  // Q = rope(LN(x@wq))
  k_gemm_bt<float><<<dim3(MQ / 128, NQK / 128), dim3(256), 0, stream>>>(xb, wqt, tmp, MQ, NQK, D);
  k_ln_rope<2048, true><<<dim3(MQ), dim3(256), 0, stream>>>(tmp, qnw, qnb, fc, fs, Qb, S - 1);
  // K = rope(LN(x@wk))
  k_gemm_bt<float><<<dim3(MQ / 128, NKVd / 128), dim3(256), 0, stream>>>(xb, wkt, tmp, MQ, NKVd, D);
  k_ln_rope<512, true><<<dim3(MQ), dim3(256), 0, stream>>>(tmp, knw, knb, fc, fs, Kb, S - 1);
  // V = x@wv (bf16 out)
  k_gemm_bt<bf16_t><<<dim3(MQ / 128, NKVd / 128), dim3(256), 0, stream>>>(xb, wvt, Vb, MQ, NKVd, D);
  // yK = LN(y@wk_y) (no rope)
  k_gemm_bt<float><<<dim3(MY / 128, NKVd / 128), dim3(256), 0, stream>>>(yb, wkyt, tmp, MY, NKVd, YD);
  k_ln_rope<512, false><<<dim3(MY), dim3(256), 0, stream>>>(tmp, kynw, kynb, fc, fs, yKb, 0);
  // yV = y@wv_y
  k_gemm_bt<bf16_t><<<dim3(MY / 128, NKVd / 128), dim3(256), 0, stream>>>(yb, wvyt, yVb, MY, NKVd, YD);
  // fused self + gated cross attention
  k_attn<<<dim3(S / 64, NH, B), dim3(256), 0, stream>>>(Qb, Kb, Vb, yKb, yVb, gate, attb, S, YLv);
  // out = att @ wo
  k_gemm_bt<float><<<dim3(MQ / 128, D / 128), dim3(256), 0, stream>>>(attb, wot, outp, MQ, D, NQK);
}

// Round 7
// 682.403 us; speedup vs baseline: 1.1625x; 1.1625x over previous
//
#include <hip/hip_runtime.h>

typedef __bf16 bf16_t;
typedef bf16_t bf16x8 __attribute__((ext_vector_type(8)));
typedef bf16_t bf16x4 __attribute__((ext_vector_type(4)));
typedef float f32x4 __attribute__((ext_vector_type(4)));

#define MFMA(a, b, c) __builtin_amdgcn_mfma_f32_16x16x32_bf16((a), (b), (c), 0, 0, 0)

// async global->LDS, 16B per lane (dest = wave-uniform base + lane*16, linear)
typedef __attribute__((address_space(1))) const unsigned int gas_u32;
typedef __attribute__((address_space(3))) unsigned int las_u32;
__device__ __forceinline__ void gload16(const bf16_t* g, bf16_t* l) {
  __builtin_amdgcn_global_load_lds((gas_u32*)g, (las_u32*)l, 16, 0, 0);
}

// ---------------- f32 -> bf16 convert (vectorized, 8 elems/thread) ----------------
__global__ __launch_bounds__(256) void k_cvt_bf16(const float* __restrict__ in,
                                                  bf16_t* __restrict__ out, long n) {
  long i = ((long)blockIdx.x * 256 + threadIdx.x) * 8;
  if (i >= n) return;
  float4 a = *(const float4*)(in + i);
  float4 b = *(const float4*)(in + i + 4);
  bf16x8 o;
  o[0] = (bf16_t)a.x; o[1] = (bf16_t)a.y; o[2] = (bf16_t)a.z; o[3] = (bf16_t)a.w;
  o[4] = (bf16_t)b.x; o[5] = (bf16_t)b.y; o[6] = (bf16_t)b.z; o[7] = (bf16_t)b.w;
  *(bf16x8*)(out + i) = o;
}

// ---------------- transpose (K,N) f32 -> (N,K) bf16, 32x32 LDS tiles ----------------
__global__ __launch_bounds__(256) void k_transpose_bf16(const float* __restrict__ in,
                                                        bf16_t* __restrict__ out,
                                                        int K, int N) {
  __shared__ float t[32][33];
  int k0 = blockIdx.x * 32, n0 = blockIdx.y * 32;
  int tx = threadIdx.x & 31, ty = threadIdx.x >> 5;  // 32 x 8
#pragma unroll
  for (int r = 0; r < 4; ++r)
    t[ty + r * 8][tx] = in[(long)(k0 + ty + r * 8) * N + n0 + tx];
  __syncthreads();
#pragma unroll
  for (int r = 0; r < 4; ++r)
    out[(long)(n0 + ty + r * 8) * K + k0 + tx] = (bf16_t)t[tx][ty + r * 8];
}

// ---------------- transpose bf16 V: [B*S][512] -> [B*512][S] (per-batch) ----------
// out[(b*512 + c)*S + s] = in[(b*S + s)*512 + c]
__global__ __launch_bounds__(256) void k_transpose_v(const bf16_t* __restrict__ in,
                                                     bf16_t* __restrict__ out, int S) {
  __shared__ bf16_t t[32][33];
  int s0 = blockIdx.x * 32, c0 = blockIdx.y * 32, b = blockIdx.z;
  int tx = threadIdx.x & 31, ty = threadIdx.x >> 5;  // 32 x 8
#pragma unroll
  for (int r = 0; r < 4; ++r)
    t[ty + r * 8][tx] = in[(long)(b * S + s0 + ty + r * 8) * 512 + c0 + tx];
  __syncthreads();
#pragma unroll
  for (int r = 0; r < 4; ++r)
    out[(long)(b * 512 + c0 + ty + r * 8) * S + s0 + tx] = t[tx][ty + r * 8];
}

// ---------------- GEMM: C[M,N] = A[M,K] * Bt[N,K]^T  (bf16 MFMA, fp32 acc) --------
// 128x128 tile, BK=32, 4 waves each 64x64. m97 structure: global_load_lds width=16,
// linear LDS [128][32] (reads are min-aliased: bank = 4*(l16+lg) pattern).
template <typename OUT_T>
__global__ __launch_bounds__(256) void k_gemm_bt(const bf16_t* __restrict__ A,
                                                 const bf16_t* __restrict__ Bt,
                                                 OUT_T* __restrict__ C,
                                                 int M, int N, int K) {
  __shared__ bf16_t Al[128 * 32];
  __shared__ bf16_t Bl[128 * 32];
  int tid = threadIdx.x;
  int lane = tid & 63, w = tid >> 6;
  int l16 = lane & 15, lg = lane >> 4;
  int m0 = blockIdx.x * 128, n0 = blockIdx.y * 128;
  int wm = (w >> 1) * 64, wn = (w & 1) * 64;

  // chunk tid -> row=tid>>2 (0..63), koff=(tid&3)*8; chunk tid+256 -> row+64.
  // LDS linear offset = chunk*16B = row*32 + (tid&3)*8 elems.
  int row0 = tid >> 2, koff = (tid & 3) * 8;
  const bf16_t* Ag0 = A + (long)(m0 + row0) * K + koff;
  const bf16_t* Ag1 = A + (long)(m0 + row0 + 64) * K + koff;
  const bf16_t* Bg0 = Bt + (long)(n0 + row0) * K + koff;
  const bf16_t* Bg1 = Bt + (long)(n0 + row0 + 64) * K + koff;
  bf16_t* Ald = Al + tid * 8;
  bf16_t* Bld = Bl + tid * 8;

  f32x4 acc[4][4] = {};

  for (int k0 = 0; k0 < K; k0 += 32) {
    __syncthreads();  // previous iter's ds_reads complete before overwrite
    gload16(Ag0 + k0, Ald);
    gload16(Ag1 + k0, Ald + 2048);
    gload16(Bg0 + k0, Bld);
    gload16(Bg1 + k0, Bld + 2048);
    __syncthreads();  // vmcnt(0) drained by compiler before barrier
    bf16x8 af[4], bfr[4];
#pragma unroll
    for (int mf = 0; mf < 4; ++mf)
      af[mf] = *(const bf16x8*)(Al + (wm + mf * 16 + l16) * 32 + lg * 8);
#pragma unroll
    for (int nf = 0; nf < 4; ++nf)
      bfr[nf] = *(const bf16x8*)(Bl + (wn + nf * 16 + l16) * 32 + lg * 8);
#pragma unroll
    for (int mf = 0; mf < 4; ++mf)
#pragma unroll
      for (int nf = 0; nf < 4; ++nf)
        acc[mf][nf] = MFMA(af[mf], bfr[nf], acc[mf][nf]);
  }

#pragma unroll
  for (int mf = 0; mf < 4; ++mf)
#pragma unroll
    for (int nf = 0; nf < 4; ++nf)
#pragma unroll
      for (int r = 0; r < 4; ++r) {
        int row = m0 + wm + mf * 16 + lg * 4 + r;
        int col = n0 + wn + nf * 16 + l16;
        C[(long)row * N + col] = (OUT_T)acc[mf][nf][r];
      }
}

// ---------------- fused LayerNorm (+optional RoPE), fp32 in -> bf16 out -----------
template <int C, bool ROPE>
__global__ __launch_bounds__(256) void k_ln_rope(const float* __restrict__ in,
                                                 const float* __restrict__ gw,
                                                 const float* __restrict__ gb,
                                                 const float* __restrict__ fc,
                                                 const float* __restrict__ fs,
                                                 bf16_t* __restrict__ out, int smask) {
  int row = blockIdx.x;
  int tid = threadIdx.x;
  const float* x = in + (long)row * C;
  float s = 0.f, ss = 0.f;
  for (int i = tid * 4; i < C; i += 1024) {
    float4 v = *(const float4*)(x + i);
    s += v.x + v.y + v.z + v.w;
    ss += v.x * v.x + v.y * v.y + v.z * v.z + v.w * v.w;
  }
#pragma unroll
  for (int msk = 1; msk < 64; msk <<= 1) {
    s += __shfl_xor(s, msk);
    ss += __shfl_xor(ss, msk);
  }
  __shared__ float rs[2][4];
  int w = tid >> 6, lane = tid & 63;
  if (lane == 0) { rs[0][w] = s; rs[1][w] = ss; }
  __syncthreads();
  s = rs[0][0] + rs[0][1] + rs[0][2] + rs[0][3];
  ss = rs[1][0] + rs[1][1] + rs[1][2] + rs[1][3];
  float mean = s * (1.0f / (float)C);
  float inv = rsqrtf(ss * (1.0f / (float)C) - mean * mean + 1e-5f);
  int srow = row & smask;
  for (int i = tid * 4; i < C; i += 1024) {
    float4 v = *(const float4*)(x + i);
    float n0 = (v.x - mean) * inv * gw[i + 0] + gb[i + 0];
    float n1 = (v.y - mean) * inv * gw[i + 1] + gb[i + 1];
    float n2 = (v.z - mean) * inv * gw[i + 2] + gb[i + 2];
    float n3 = (v.w - mean) * inv * gw[i + 3] + gb[i + 3];
    bf16x4 o;
    if (ROPE) {
      int dh = i & 63;
      int f0 = dh >> 1, f1 = f0 + 1;
      float c0 = fc[srow * 32 + f0], s0 = fs[srow * 32 + f0];
      float c1 = fc[srow * 32 + f1], s1 = fs[srow * 32 + f1];
      o[0] = (bf16_t)(n0 * c0 - n1 * s0);
      o[1] = (bf16_t)(n0 * s0 + n1 * c0);
      o[2] = (bf16_t)(n2 * c1 - n3 * s1);
      o[3] = (bf16_t)(n2 * s1 + n3 * c1);
    } else {
      o[0] = (bf16_t)n0; o[1] = (bf16_t)n1; o[2] = (bf16_t)n2; o[3] = (bf16_t)n3;
    }
    *(bf16x4*)(out + (long)row * C + i) = o;
  }
}

// ---------------- fused GQA attention: self (S keys) + gated cross (YL keys) -------
// V comes PRE-TRANSPOSED in global ([B*512][seq]) so LDS staging is vectorized b128
// (kills the former 16-way scatter conflict, 8.7e7 SQ_LDS_BANK_CONFLICT).
__global__ __launch_bounds__(256) void k_attn(const bf16_t* __restrict__ Q,
                                              const bf16_t* __restrict__ Kx,
                                              const bf16_t* __restrict__ Vxt,
                                              const bf16_t* __restrict__ Ky,
                                              const bf16_t* __restrict__ Vyt,
                                              const float* __restrict__ gate,
                                              bf16_t* __restrict__ out, int S, int YL) {
  __shared__ bf16_t Kl[64 * 72];     // [key][d] padded to 72 (144B rows)
  __shared__ bf16_t Vt[64 * 72];     // [d][key] padded
  __shared__ bf16_t Pl[4][16 * 72];  // per-wave P tile [qrow][key] padded

  int tid = threadIdx.x;
  int lane = tid & 63, w = tid >> 6;
  int l16 = lane & 15, lg = lane >> 4;
  int qt = blockIdx.x, h = blockIdx.y, b = blockIdx.z;
  int kv = h >> 2;  // n_rep = 4

  bf16x8 qf[2];
  {
    long qoff = ((long)(b * S + qt * 64 + w * 16 + l16)) * 2048 + h * 64;
    qf[0] = *(const bf16x8*)(Q + qoff + lg * 8);
    qf[1] = *(const bf16x8*)(Q + qoff + 32 + lg * 8);
  }

  int kr0 = tid >> 3, kb0 = tid & 7;  // kr0 0..31; chunk2 rows +32

  float res[4][4];
  float tg = tanhf(gate[h]);

  for (int phase = 0; phase < 2; ++phase) {
    const bf16_t* Kg = phase ? (Ky + (long)b * YL * 512 + kv * 64)
                             : (Kx + (long)b * S * 512 + kv * 64);
    const bf16_t* Vg = phase ? (Vyt + (long)(b * 8 + kv) * 64 * YL)
                             : (Vxt + (long)(b * 8 + kv) * 64 * S);
    int Sv = phase ? YL : S;
    int nt = Sv >> 6;

    float mr[4], lr[4];
    f32x4 o[4] = {};
#pragma unroll
    for (int r = 0; r < 4; ++r) { mr[r] = -1e30f; lr[r] = 0.f; }

    for (int t = 0; t < nt; ++t) {
      const bf16_t* kt = Kg + (long)t * 64 * 512;
      const bf16_t* vtp = Vg + t * 64;
      bf16x8 kc0 = *(const bf16x8*)(kt + kr0 * 512 + kb0 * 8);
      bf16x8 kc1 = *(const bf16x8*)(kt + (kr0 + 32) * 512 + kb0 * 8);
      bf16x8 vc0 = *(const bf16x8*)(vtp + (long)kr0 * Sv + kb0 * 8);
      bf16x8 vc1 = *(const bf16x8*)(vtp + (long)(kr0 + 32) * Sv + kb0 * 8);
      __syncthreads();  // prior tile's LDS reads done
      *(bf16x8*)(Kl + kr0 * 72 + kb0 * 8) = kc0;
      *(bf16x8*)(Kl + (kr0 + 32) * 72 + kb0 * 8) = kc1;
      *(bf16x8*)(Vt + kr0 * 72 + kb0 * 8) = vc0;   // row=d, col=key: b128, clean
      *(bf16x8*)(Vt + (kr0 + 32) * 72 + kb0 * 8) = vc1;
      __syncthreads();

      // scores S[q][key] = Q . K^T (scaled)
      f32x4 sc[4] = {};
      __builtin_amdgcn_s_setprio(1);
#pragma unroll
      for (int kf = 0; kf < 2; ++kf)
#pragma unroll
        for (int nf = 0; nf < 4; ++nf) {
          bf16x8 kfr = *(const bf16x8*)(Kl + (nf * 16 + l16) * 72 + kf * 32 + lg * 8);
          sc[nf] = MFMA(qf[kf], kfr, sc[nf]);
        }
      __builtin_amdgcn_s_setprio(0);
      float tmax[4], tsum[4], al[4];
#pragma unroll
      for (int nf = 0; nf < 4; ++nf) sc[nf] *= 0.125f;  // 1/sqrt(64)
#pragma unroll
      for (int r = 0; r < 4; ++r) {
        tmax[r] = fmaxf(fmaxf(sc[0][r], sc[1][r]), fmaxf(sc[2][r], sc[3][r]));
#pragma unroll
        for (int msk = 1; msk < 16; msk <<= 1)
          tmax[r] = fmaxf(tmax[r], __shfl_xor(tmax[r], msk));
        float mn = fmaxf(mr[r], tmax[r]);
        al[r] = __expf(mr[r] - mn);
        mr[r] = mn;
        tsum[r] = 0.f;
      }
#pragma unroll
      for (int nf = 0; nf < 4; ++nf)
#pragma unroll
        for (int r = 0; r < 4; ++r) {
          float p = __expf(sc[nf][r] - mr[r]);
          sc[nf][r] = p;
          tsum[r] += p;
        }
#pragma unroll
      for (int r = 0; r < 4; ++r) {
#pragma unroll
        for (int msk = 1; msk < 16; msk <<= 1) tsum[r] += __shfl_xor(tsum[r], msk);
        lr[r] = lr[r] * al[r] + tsum[r];
      }
#pragma unroll
      for (int df = 0; df < 4; ++df)
#pragma unroll
        for (int r = 0; r < 4; ++r) o[df][r] *= al[r];
      // P -> LDS (D-layout rows lg*4+r) then re-read in A-layout (same wave, lgkmcnt)
#pragma unroll
      for (int nf = 0; nf < 4; ++nf)
#pragma unroll
        for (int r = 0; r < 4; ++r)
          Pl[w][(lg * 4 + r) * 72 + nf * 16 + l16] = (bf16_t)sc[nf][r];
      __builtin_amdgcn_s_setprio(1);
#pragma unroll
      for (int kb = 0; kb < 2; ++kb) {
        bf16x8 pa = *(const bf16x8*)(&Pl[w][l16 * 72 + kb * 32 + lg * 8]);
#pragma unroll
        for (int df = 0; df < 4; ++df) {
          bf16x8 vb = *(const bf16x8*)(Vt + (df * 16 + l16) * 72 + kb * 32 + lg * 8);
          o[df] = MFMA(pa, vb, o[df]);
        }
      }
      __builtin_amdgcn_s_setprio(0);
    }
#pragma unroll
    for (int df = 0; df < 4; ++df)
#pragma unroll
      for (int r = 0; r < 4; ++r) {
        float v = o[df][r] / lr[r];
        if (phase == 0) res[df][r] = v;
        else res[df][r] += tg * v;
      }
  }

  long obase = ((long)(b * S + qt * 64 + w * 16 + lg * 4)) * 2048 + h * 64 + l16;
#pragma unroll
  for (int df = 0; df < 4; ++df)
#pragma unroll
    for (int r = 0; r < 4; ++r)
      out[obase + (long)r * 2048 + df * 16] = (bf16_t)res[df][r];
}

// ------------------------------- launch ------------------------------------------
extern "C" void kernel_launch(void* const* d_in, const int* in_sizes, int n_in,
                              void* d_out, int out_size, void* d_ws, size_t ws_size,
                              hipStream_t stream) {
  const float* x    = (const float*)d_in[0];
  const float* fc   = (const float*)d_in[2];
  const float* fs   = (const float*)d_in[3];
  const float* y    = (const float*)d_in[4];
  const float* wq   = (const float*)d_in[6];
  const float* wk   = (const float*)d_in[7];
  const float* wv   = (const float*)d_in[8];
  const float* wky  = (const float*)d_in[9];
  const float* wvy  = (const float*)d_in[10];
  const float* wo   = (const float*)d_in[11];
  const float* gate = (const float*)d_in[12];
  const float* qnw  = (const float*)d_in[13];
  const float* qnb  = (const float*)d_in[14];
  const float* knw  = (const float*)d_in[15];
  const float* knb  = (const float*)d_in[16];
  const float* kynw = (const float*)d_in[17];
  const float* kynb = (const float*)d_in[18];
  float* outp = (float*)d_out;

  constexpr int B = 2, S = 2048, D = 2048, YLv = 256, YD = 1024;
  constexpr int MQ = B * S;    // 4096
  constexpr int MY = B * YLv;  // 512
  constexpr int NQK = 2048;
  constexpr int NKVd = 512;

  char* p = (char*)d_ws;
  auto alloc = [&](long bytes) { char* r = p; p += (bytes + 255) & ~255L; return r; };
  float*  tmp  = (float*)alloc((long)MQ * NQK * 4);  // LN scratch; attb aliases later
  bf16_t* xb   = (bf16_t*)alloc((long)MQ * D * 2);
  bf16_t* yb   = (bf16_t*)alloc((long)MY * YD * 2);
  bf16_t* wqt  = (bf16_t*)alloc((long)NQK * D * 2);
  bf16_t* wkt  = (bf16_t*)alloc((long)NKVd * D * 2);
  bf16_t* wvt  = (bf16_t*)alloc((long)NKVd * D * 2);
  bf16_t* wkyt = (bf16_t*)alloc((long)NKVd * YD * 2);
  bf16_t* wvyt = (bf16_t*)alloc((long)NKVd * YD * 2);
  bf16_t* wot  = (bf16_t*)alloc((long)D * NQK * 2);
  bf16_t* Qb   = (bf16_t*)alloc((long)MQ * NQK * 2);
  bf16_t* Kb   = (bf16_t*)alloc((long)MQ * NKVd * 2);
  bf16_t* Vb   = (bf16_t*)alloc((long)MQ * NKVd * 2);
  bf16_t* Vxt  = (bf16_t*)alloc((long)B * NKVd * S * 2);   // [B*512][S]
  bf16_t* yKb  = (bf16_t*)alloc((long)MY * NKVd * 2);
  bf16_t* yVb  = (bf16_t*)alloc((long)MY * NKVd * 2);
  bf16_t* yVt  = (bf16_t*)alloc((long)B * NKVd * YLv * 2); // [B*512][YL]
  bf16_t* attb = (bf16_t*)tmp;  // overlay: tmp's last read precedes k_attn's write

  // activations -> bf16
  k_cvt_bf16<<<dim3(((long)MQ * D) / 2048), dim3(256), 0, stream>>>(x, xb, (long)MQ * D);
  k_cvt_bf16<<<dim3(((long)MY * YD) / 2048), dim3(256), 0, stream>>>(y, yb, (long)MY * YD);
  // weights -> transposed bf16 (N,K)
  k_transpose_bf16<<<dim3(D / 32, NQK / 32), dim3(256), 0, stream>>>(wq, wqt, D, NQK);
  k_transpose_bf16<<<dim3(D / 32, NKVd / 32), dim3(256), 0, stream>>>(wk, wkt, D, NKVd);
  k_transpose_bf16<<<dim3(D / 32, NKVd / 32), dim3(256), 0, stream>>>(wv, wvt, D, NKVd);
  k_transpose_bf16<<<dim3(YD / 32, NKVd / 32), dim3(256), 0, stream>>>(wky, wkyt, YD, NKVd);
  k_transpose_bf16<<<dim3(YD / 32, NKVd / 32), dim3(256), 0, stream>>>(wvy, wvyt, YD, NKVd);
  k_transpose_bf16<<<dim3(NQK / 32, D / 32), dim3(256), 0, stream>>>(wo, wot, NQK, D);

  // Q = rope(LN(x@wq))
  k_gemm_bt<float><<<dim3(MQ / 128, NQK / 128), dim3(256), 0, stream>>>(xb, wqt, tmp, MQ, NQK, D);
  k_ln_rope<2048, true><<<dim3(MQ), dim3(256), 0, stream>>>(tmp, qnw, qnb, fc, fs, Qb, S - 1);
  // K = rope(LN(x@wk))
  k_gemm_bt<float><<<dim3(MQ / 128, NKVd / 128), dim3(256), 0, stream>>>(xb, wkt, tmp, MQ, NKVd, D);
  k_ln_rope<512, true><<<dim3(MQ), dim3(256), 0, stream>>>(tmp, knw, knb, fc, fs, Kb, S - 1);
  // V = x@wv (bf16), then pre-transpose per batch: [B*S][512] -> [B*512][S]
  k_gemm_bt<bf16_t><<<dim3(MQ / 128, NKVd / 128), dim3(256), 0, stream>>>(xb, wvt, Vb, MQ, NKVd, D);
  k_transpose_v<<<dim3(S / 32, NKVd / 32, B), dim3(256), 0, stream>>>(Vb, Vxt, S);
  // yK = LN(y@wk_y) (no rope)
  k_gemm_bt<float><<<dim3(MY / 128, NKVd / 128), dim3(256), 0, stream>>>(yb, wkyt, tmp, MY, NKVd, YD);
  k_ln_rope<512, false><<<dim3(MY), dim3(256), 0, stream>>>(tmp, kynw, kynb, fc, fs, yKb, 0);
  // yV = y@wv_y, pre-transposed
  k_gemm_bt<bf16_t><<<dim3(MY / 128, NKVd / 128), dim3(256), 0, stream>>>(yb, wvyt, yVb, MY, NKVd, YD);
  k_transpose_v<<<dim3(YLv / 32, NKVd / 32, B), dim3(256), 0, stream>>>(yVb, yVt, YLv);
  // fused self + gated cross attention
  k_attn<<<dim3(S / 64, 32, B), dim3(256), 0, stream>>>(Qb, Kb, Vxt, yKb, yVt, gate, attb, S, YLv);
  // out = att @ wo
  k_gemm_bt<float><<<dim3(MQ / 128, D / 128), dim3(256), 0, stream>>>(attb, wot, outp, MQ, D, NQK);
}

// Round 8
// 518.576 us; speedup vs baseline: 1.5297x; 1.3159x over previous
//
#include <hip/hip_runtime.h>

typedef __bf16 bf16_t;
typedef bf16_t bf16x8 __attribute__((ext_vector_type(8)));
typedef bf16_t bf16x4 __attribute__((ext_vector_type(4)));
typedef float f32x4 __attribute__((ext_vector_type(4)));

#define MFMA(a, b, c) __builtin_amdgcn_mfma_f32_16x16x32_bf16((a), (b), (c), 0, 0, 0)

// async global->LDS, 16B per lane (dest = wave-uniform base + lane*16, linear)
typedef __attribute__((address_space(1))) const unsigned int gas_u32;
typedef __attribute__((address_space(3))) unsigned int las_u32;
__device__ __forceinline__ void gload16(const bf16_t* g, bf16_t* l) {
  __builtin_amdgcn_global_load_lds((gas_u32*)g, (las_u32*)l, 16, 0, 0);
}

// ---------------- f32 -> bf16 convert (vectorized, 8 elems/thread) ----------------
__global__ __launch_bounds__(256) void k_cvt_bf16(const float* __restrict__ in,
                                                  bf16_t* __restrict__ out, long n) {
  long i = ((long)blockIdx.x * 256 + threadIdx.x) * 8;
  if (i >= n) return;
  float4 a = *(const float4*)(in + i);
  float4 b = *(const float4*)(in + i + 4);
  bf16x8 o;
  o[0] = (bf16_t)a.x; o[1] = (bf16_t)a.y; o[2] = (bf16_t)a.z; o[3] = (bf16_t)a.w;
  o[4] = (bf16_t)b.x; o[5] = (bf16_t)b.y; o[6] = (bf16_t)b.z; o[7] = (bf16_t)b.w;
  *(bf16x8*)(out + i) = o;
}

// ---------------- transpose (K,N) f32 -> (N,K) bf16, 32x32 LDS tiles --------------
// out row stride = K (pass sub-buffer base for concatenated weights)
__global__ __launch_bounds__(256) void k_transpose_bf16(const float* __restrict__ in,
                                                        bf16_t* __restrict__ out,
                                                        int K, int N) {
  __shared__ float t[32][33];
  int k0 = blockIdx.x * 32, n0 = blockIdx.y * 32;
  int tx = threadIdx.x & 31, ty = threadIdx.x >> 5;  // 32 x 8
#pragma unroll
  for (int r = 0; r < 4; ++r)
    t[ty + r * 8][tx] = in[(long)(k0 + ty + r * 8) * N + n0 + tx];
  __syncthreads();
#pragma unroll
  for (int r = 0; r < 4; ++r)
    out[(long)(n0 + ty + r * 8) * K + k0 + tx] = (bf16_t)t[tx][ty + r * 8];
}

// ------- transpose V slice: fp32 [B*S][LD] (pre-offset to V cols) -> bf16 [B*512][S]
__global__ __launch_bounds__(256) void k_transpose_vf(const float* __restrict__ in,
                                                      bf16_t* __restrict__ out,
                                                      int S, int LD) {
  __shared__ float t[32][33];
  int s0 = blockIdx.x * 32, c0 = blockIdx.y * 32, b = blockIdx.z;
  int tx = threadIdx.x & 31, ty = threadIdx.x >> 5;  // 32 x 8
#pragma unroll
  for (int r = 0; r < 4; ++r)
    t[ty + r * 8][tx] = in[(long)(b * S + s0 + ty + r * 8) * LD + c0 + tx];
  __syncthreads();
#pragma unroll
  for (int r = 0; r < 4; ++r)
    out[(long)(b * 512 + c0 + ty + r * 8) * S + s0 + tx] = (bf16_t)t[tx][ty + r * 8];
}

// ---------------- GEMM: C[M,N] = A[M,K] * Bt[N,K]^T  (bf16 MFMA, fp32 acc) --------
// 128x128 tile, BK=32, 4 waves each 64x64. m97 structure (global_load_lds w=16).
template <typename OUT_T>
__global__ __launch_bounds__(256) void k_gemm_bt(const bf16_t* __restrict__ A,
                                                 const bf16_t* __restrict__ Bt,
                                                 OUT_T* __restrict__ C,
                                                 int M, int N, int K) {
  __shared__ bf16_t Al[128 * 32];
  __shared__ bf16_t Bl[128 * 32];
  int tid = threadIdx.x;
  int lane = tid & 63, w = tid >> 6;
  int l16 = lane & 15, lg = lane >> 4;
  int m0 = blockIdx.x * 128, n0 = blockIdx.y * 128;
  int wm = (w >> 1) * 64, wn = (w & 1) * 64;

  int row0 = tid >> 2, koff = (tid & 3) * 8;
  const bf16_t* Ag0 = A + (long)(m0 + row0) * K + koff;
  const bf16_t* Ag1 = A + (long)(m0 + row0 + 64) * K + koff;
  const bf16_t* Bg0 = Bt + (long)(n0 + row0) * K + koff;
  const bf16_t* Bg1 = Bt + (long)(n0 + row0 + 64) * K + koff;
  bf16_t* Ald = Al + tid * 8;
  bf16_t* Bld = Bl + tid * 8;

  f32x4 acc[4][4] = {};

  for (int k0 = 0; k0 < K; k0 += 32) {
    __syncthreads();
    gload16(Ag0 + k0, Ald);
    gload16(Ag1 + k0, Ald + 2048);
    gload16(Bg0 + k0, Bld);
    gload16(Bg1 + k0, Bld + 2048);
    __syncthreads();
    bf16x8 af[4], bfr[4];
#pragma unroll
    for (int mf = 0; mf < 4; ++mf)
      af[mf] = *(const bf16x8*)(Al + (wm + mf * 16 + l16) * 32 + lg * 8);
#pragma unroll
    for (int nf = 0; nf < 4; ++nf)
      bfr[nf] = *(const bf16x8*)(Bl + (wn + nf * 16 + l16) * 32 + lg * 8);
#pragma unroll
    for (int mf = 0; mf < 4; ++mf)
#pragma unroll
      for (int nf = 0; nf < 4; ++nf)
        acc[mf][nf] = MFMA(af[mf], bfr[nf], acc[mf][nf]);
  }

#pragma unroll
  for (int mf = 0; mf < 4; ++mf)
#pragma unroll
    for (int nf = 0; nf < 4; ++nf)
#pragma unroll
      for (int r = 0; r < 4; ++r) {
        int row = m0 + wm + mf * 16 + lg * 4 + r;
        int col = n0 + wn + nf * 16 + l16;
        C[(long)row * N + col] = (OUT_T)acc[mf][nf][r];
      }
}

// ---------------- fused LayerNorm (+optional RoPE), fp32 in -> bf16 out -----------
// LN over C cols of a row whose input stride is LD (supports concatenated KV output).
template <int C, bool ROPE>
__global__ __launch_bounds__(256) void k_ln_rope(const float* __restrict__ in,
                                                 const float* __restrict__ gw,
                                                 const float* __restrict__ gb,
                                                 const float* __restrict__ fc,
                                                 const float* __restrict__ fs,
                                                 bf16_t* __restrict__ out,
                                                 int smask, int LD) {
  int row = blockIdx.x;
  int tid = threadIdx.x;
  const float* x = in + (long)row * LD;
  float s = 0.f, ss = 0.f;
  for (int i = tid * 4; i < C; i += 1024) {
    float4 v = *(const float4*)(x + i);
    s += v.x + v.y + v.z + v.w;
    ss += v.x * v.x + v.y * v.y + v.z * v.z + v.w * v.w;
  }
#pragma unroll
  for (int msk = 1; msk < 64; msk <<= 1) {
    s += __shfl_xor(s, msk);
    ss += __shfl_xor(ss, msk);
  }
  __shared__ float rs[2][4];
  int w = tid >> 6, lane = tid & 63;
  if (lane == 0) { rs[0][w] = s; rs[1][w] = ss; }
  __syncthreads();
  s = rs[0][0] + rs[0][1] + rs[0][2] + rs[0][3];
  ss = rs[1][0] + rs[1][1] + rs[1][2] + rs[1][3];
  float mean = s * (1.0f / (float)C);
  float inv = rsqrtf(ss * (1.0f / (float)C) - mean * mean + 1e-5f);
  int srow = row & smask;
  for (int i = tid * 4; i < C; i += 1024) {
    float4 v = *(const float4*)(x + i);
    float n0 = (v.x - mean) * inv * gw[i + 0] + gb[i + 0];
    float n1 = (v.y - mean) * inv * gw[i + 1] + gb[i + 1];
    float n2 = (v.z - mean) * inv * gw[i + 2] + gb[i + 2];
    float n3 = (v.w - mean) * inv * gw[i + 3] + gb[i + 3];
    bf16x4 o;
    if (ROPE) {
      int dh = i & 63;
      int f0 = dh >> 1, f1 = f0 + 1;
      float c0 = fc[srow * 32 + f0], s0 = fs[srow * 32 + f0];
      float c1 = fc[srow * 32 + f1], s1 = fs[srow * 32 + f1];
      o[0] = (bf16_t)(n0 * c0 - n1 * s0);
      o[1] = (bf16_t)(n0 * s0 + n1 * c0);
      o[2] = (bf16_t)(n2 * c1 - n3 * s1);
      o[3] = (bf16_t)(n2 * s1 + n3 * c1);
    } else {
      o[0] = (bf16_t)n0; o[1] = (bf16_t)n1; o[2] = (bf16_t)n2; o[3] = (bf16_t)n3;
    }
    *(bf16x4*)(out + (long)row * C + i) = o;
  }
}

// ---------------- fused GQA attention: self (S keys) + gated cross (YL keys) -------
// Fixed-max softmax (M=20, shift-invariant => exact): no running max, no rescale,
// no per-tile reduces. Per-lane partial sums; one shuffle-reduce per phase.
// Async-stage split: next tile's global loads issue before compute (T14).
__global__ __launch_bounds__(256) void k_attn(const bf16_t* __restrict__ Q,
                                              const bf16_t* __restrict__ Kx,
                                              const bf16_t* __restrict__ Vxt,
                                              const bf16_t* __restrict__ Ky,
                                              const bf16_t* __restrict__ Vyt,
                                              const float* __restrict__ gate,
                                              bf16_t* __restrict__ out, int S, int YL) {
  __shared__ bf16_t Kl[64 * 72];     // [key][d] padded to 72
  __shared__ bf16_t Vt[64 * 72];     // [d][key] padded
  __shared__ bf16_t Pl[4][16 * 72];  // per-wave P tile [qrow][key] padded

  int tid = threadIdx.x;
  int lane = tid & 63, w = tid >> 6;
  int l16 = lane & 15, lg = lane >> 4;
  int qt = blockIdx.x, h = blockIdx.y, b = blockIdx.z;
  int kv = h >> 2;  // n_rep = 4

  bf16x8 qf[2];
  {
    long qoff = ((long)(b * S + qt * 64 + w * 16 + l16)) * 2048 + h * 64;
    qf[0] = *(const bf16x8*)(Q + qoff + lg * 8);
    qf[1] = *(const bf16x8*)(Q + qoff + 32 + lg * 8);
    // fold 1/sqrt(64) into Q (0.125 = exponent shift, exact in bf16)
#pragma unroll
    for (int j = 0; j < 8; ++j) {
      qf[0][j] = (bf16_t)((float)qf[0][j] * 0.125f);
      qf[1][j] = (bf16_t)((float)qf[1][j] * 0.125f);
    }
  }

  int kr0 = tid >> 3, kb0 = tid & 7;  // kr0 0..31; second chunk rows +32

  float res[4][4];
  float tg = tanhf(gate[h]);

  for (int phase = 0; phase < 2; ++phase) {
    const bf16_t* Kg = phase ? (Ky + (long)b * YL * 512 + kv * 64)
                             : (Kx + (long)b * S * 512 + kv * 64);
    const bf16_t* Vg = phase ? (Vyt + (long)(b * 8 + kv) * 64 * YL)
                             : (Vxt + (long)(b * 8 + kv) * 64 * S);
    int Sv = phase ? YL : S;
    int nt = Sv >> 6;

    float lrp[4] = {0.f, 0.f, 0.f, 0.f};
    f32x4 o[4] = {};

    // prologue: load tile 0 into regs
    bf16x8 kc0, kc1, vc0, vc1;
    {
      const bf16_t* kt = Kg;
      const bf16_t* vtp = Vg;
      kc0 = *(const bf16x8*)(kt + kr0 * 512 + kb0 * 8);
      kc1 = *(const bf16x8*)(kt + (kr0 + 32) * 512 + kb0 * 8);
      vc0 = *(const bf16x8*)(vtp + (long)kr0 * Sv + kb0 * 8);
      vc1 = *(const bf16x8*)(vtp + (long)(kr0 + 32) * Sv + kb0 * 8);
    }

    for (int t = 0; t < nt; ++t) {
      __syncthreads();  // prior tile's LDS reads done
      *(bf16x8*)(Kl + kr0 * 72 + kb0 * 8) = kc0;
      *(bf16x8*)(Kl + (kr0 + 32) * 72 + kb0 * 8) = kc1;
      *(bf16x8*)(Vt + kr0 * 72 + kb0 * 8) = vc0;
      *(bf16x8*)(Vt + (kr0 + 32) * 72 + kb0 * 8) = vc1;
      __syncthreads();

      if (t + 1 < nt) {  // async-stage: issue next tile's loads; latency hides under compute
        const bf16_t* kt = Kg + (long)(t + 1) * 64 * 512;
        const bf16_t* vtp = Vg + (t + 1) * 64;
        kc0 = *(const bf16x8*)(kt + kr0 * 512 + kb0 * 8);
        kc1 = *(const bf16x8*)(kt + (kr0 + 32) * 512 + kb0 * 8);
        vc0 = *(const bf16x8*)(vtp + (long)kr0 * Sv + kb0 * 8);
        vc1 = *(const bf16x8*)(vtp + (long)(kr0 + 32) * Sv + kb0 * 8);
      }

      // scores (Q pre-scaled)
      f32x4 sc[4] = {};
      __builtin_amdgcn_s_setprio(1);
#pragma unroll
      for (int kf = 0; kf < 2; ++kf)
#pragma unroll
        for (int nf = 0; nf < 4; ++nf) {
          bf16x8 kfr = *(const bf16x8*)(Kl + (nf * 16 + l16) * 72 + kf * 32 + lg * 8);
          sc[nf] = MFMA(qf[kf], kfr, sc[nf]);
        }
      __builtin_amdgcn_s_setprio(0);

      // fixed-max softmax: P = exp(s - 20); partial sums per-lane, no reduces here
#pragma unroll
      for (int nf = 0; nf < 4; ++nf)
#pragma unroll
        for (int r = 0; r < 4; ++r) {
          float p = __expf(sc[nf][r] - 20.0f);
          lrp[r] += p;
          Pl[w][(lg * 4 + r) * 72 + nf * 16 + l16] = (bf16_t)p;
        }

      __builtin_amdgcn_s_setprio(1);
#pragma unroll
      for (int kb = 0; kb < 2; ++kb) {
        bf16x8 pa = *(const bf16x8*)(&Pl[w][l16 * 72 + kb * 32 + lg * 8]);
#pragma unroll
        for (int df = 0; df < 4; ++df) {
          bf16x8 vb = *(const bf16x8*)(Vt + (df * 16 + l16) * 72 + kb * 32 + lg * 8);
          o[df] = MFMA(pa, vb, o[df]);
        }
      }
      __builtin_amdgcn_s_setprio(0);
    }

    // one reduce per phase: sum lrp over the 16 lanes sharing lg
    float inv[4];
#pragma unroll
    for (int r = 0; r < 4; ++r) {
      float s_ = lrp[r];
#pragma unroll
      for (int msk = 1; msk < 16; msk <<= 1) s_ += __shfl_xor(s_, msk);
      inv[r] = 1.0f / s_;
    }
#pragma unroll
    for (int df = 0; df < 4; ++df)
#pragma unroll
      for (int r = 0; r < 4; ++r) {
        float v = o[df][r] * inv[r];
        if (phase == 0) res[df][r] = v;
        else res[df][r] += tg * v;
      }
  }

  long obase = ((long)(b * S + qt * 64 + w * 16 + lg * 4)) * 2048 + h * 64 + l16;
#pragma unroll
  for (int df = 0; df < 4; ++df)
#pragma unroll
    for (int r = 0; r < 4; ++r)
      out[obase + (long)r * 2048 + df * 16] = (bf16_t)res[df][r];
}

// ------------------------------- launch ------------------------------------------
extern "C" void kernel_launch(void* const* d_in, const int* in_sizes, int n_in,
                              void* d_out, int out_size, void* d_ws, size_t ws_size,
                              hipStream_t stream) {
  const float* x    = (const float*)d_in[0];
  const float* fc   = (const float*)d_in[2];
  const float* fs   = (const float*)d_in[3];
  const float* y    = (const float*)d_in[4];
  const float* wq   = (const float*)d_in[6];
  const float* wk   = (const float*)d_in[7];
  const float* wv   = (const float*)d_in[8];
  const float* wky  = (const float*)d_in[9];
  const float* wvy  = (const float*)d_in[10];
  const float* wo   = (const float*)d_in[11];
  const float* gate = (const float*)d_in[12];
  const float* qnw  = (const float*)d_in[13];
  const float* qnb  = (const float*)d_in[14];
  const float* knw  = (const float*)d_in[15];
  const float* knb  = (const float*)d_in[16];
  const float* kynw = (const float*)d_in[17];
  const float* kynb = (const float*)d_in[18];
  float* outp = (float*)d_out;

  constexpr int B = 2, S = 2048, D = 2048, YLv = 256, YD = 1024;
  constexpr int MQ = B * S;    // 4096
  constexpr int MY = B * YLv;  // 512
  constexpr int NQK = 2048;
  constexpr int NKVd = 512;

  char* p = (char*)d_ws;
  auto alloc = [&](long bytes) { char* r = p; p += (bytes + 255) & ~255L; return r; };
  float*  tmp  = (float*)alloc((long)MQ * NQK * 4);  // shared fp32 scratch; attb aliases later
  bf16_t* xb   = (bf16_t*)alloc((long)MQ * D * 2);
  bf16_t* yb   = (bf16_t*)alloc((long)MY * YD * 2);
  bf16_t* wqt  = (bf16_t*)alloc((long)NQK * D * 2);
  bf16_t* wkvt = (bf16_t*)alloc((long)1024 * D * 2);    // [k|v] concat, rows 0-511 = wk^T
  bf16_t* wkvyt= (bf16_t*)alloc((long)1024 * YD * 2);   // [ky|vy] concat
  bf16_t* wot  = (bf16_t*)alloc((long)D * NQK * 2);
  bf16_t* Qb   = (bf16_t*)alloc((long)MQ * NQK * 2);
  bf16_t* Kb   = (bf16_t*)alloc((long)MQ * NKVd * 2);
  bf16_t* Vxt  = (bf16_t*)alloc((long)B * NKVd * S * 2);   // [B*512][S]
  bf16_t* yKb  = (bf16_t*)alloc((long)MY * NKVd * 2);
  bf16_t* yVt  = (bf16_t*)alloc((long)B * NKVd * YLv * 2); // [B*512][YL]
  bf16_t* attb = (bf16_t*)tmp;  // overlay: all tmp reads precede k_attn's write

  // activations -> bf16
  k_cvt_bf16<<<dim3(((long)MQ * D) / 2048), dim3(256), 0, stream>>>(x, xb, (long)MQ * D);
  k_cvt_bf16<<<dim3(((long)MY * YD) / 2048), dim3(256), 0, stream>>>(y, yb, (long)MY * YD);
  // weights -> transposed bf16 (N,K); k/v and ky/vy concatenated
  k_transpose_bf16<<<dim3(D / 32, NQK / 32), dim3(256), 0, stream>>>(wq, wqt, D, NQK);
  k_transpose_bf16<<<dim3(D / 32, NKVd / 32), dim3(256), 0, stream>>>(wk, wkvt, D, NKVd);
  k_transpose_bf16<<<dim3(D / 32, NKVd / 32), dim3(256), 0, stream>>>(wv, wkvt + (long)512 * D, D, NKVd);
  k_transpose_bf16<<<dim3(YD / 32, NKVd / 32), dim3(256), 0, stream>>>(wky, wkvyt, YD, NKVd);
  k_transpose_bf16<<<dim3(YD / 32, NKVd / 32), dim3(256), 0, stream>>>(wvy, wkvyt + (long)512 * YD, YD, NKVd);
  k_transpose_bf16<<<dim3(NQK / 32, D / 32), dim3(256), 0, stream>>>(wo, wot, NQK, D);

  // Q = rope(LN(x@wq))
  k_gemm_bt<float><<<dim3(MQ / 128, NQK / 128), dim3(256), 0, stream>>>(xb, wqt, tmp, MQ, NQK, D);
  k_ln_rope<2048, true><<<dim3(MQ), dim3(256), 0, stream>>>(tmp, qnw, qnb, fc, fs, Qb, S - 1, 2048);
  // KV fused: x@[wk|wv] -> tmp [4096][1024]; K = rope(LN(cols 0-511)); V^T from cols 512-1023
  k_gemm_bt<float><<<dim3(MQ / 128, 1024 / 128), dim3(256), 0, stream>>>(xb, wkvt, tmp, MQ, 1024, D);
  k_ln_rope<512, true><<<dim3(MQ), dim3(256), 0, stream>>>(tmp, knw, knb, fc, fs, Kb, S - 1, 1024);
  k_transpose_vf<<<dim3(S / 32, 16, B), dim3(256), 0, stream>>>(tmp + 512, Vxt, S, 1024);
  // yKV fused: y@[wky|wvy] -> tmp [512][1024]
  k_gemm_bt<float><<<dim3(MY / 128, 1024 / 128), dim3(256), 0, stream>>>(yb, wkvyt, tmp, MY, 1024, YD);
  k_ln_rope<512, false><<<dim3(MY), dim3(256), 0, stream>>>(tmp, kynw, kynb, fc, fs, yKb, 0, 1024);
  k_transpose_vf<<<dim3(YLv / 32, 16, B), dim3(256), 0, stream>>>(tmp + 512, yVt, YLv, 1024);
  // fused self + gated cross attention
  k_attn<<<dim3(S / 64, 32, B), dim3(256), 0, stream>>>(Qb, Kb, Vxt, yKb, yVt, gate, attb, S, YLv);
  // out = att @ wo
  k_gemm_bt<float><<<dim3(MQ / 128, D / 128), dim3(256), 0, stream>>>(attb, wot, outp, MQ, D, NQK);
}

// Round 11
// 472.869 us; speedup vs baseline: 1.6776x; 1.0967x over previous
//
#include <hip/hip_runtime.h>

typedef __bf16 bf16_t;
typedef bf16_t bf16x8 __attribute__((ext_vector_type(8)));
typedef bf16_t bf16x4 __attribute__((ext_vector_type(4)));
typedef float f32x4 __attribute__((ext_vector_type(4)));

#define MFMA(a, b, c) __builtin_amdgcn_mfma_f32_16x16x32_bf16((a), (b), (c), 0, 0, 0)

// async global->LDS, 16B per lane (dest = wave-uniform base + lane*16, linear)
typedef __attribute__((address_space(1))) const unsigned int gas_u32;
typedef __attribute__((address_space(3))) unsigned int las_u32;
__device__ __forceinline__ void gload16(const bf16_t* g, bf16_t* l) {
  __builtin_amdgcn_global_load_lds((gas_u32*)g, (las_u32*)l, 16, 0, 0);
}

// ---------------- f32 -> bf16 convert (vectorized, 8 elems/thread) ----------------
__global__ __launch_bounds__(256) void k_cvt_bf16(const float* __restrict__ in,
                                                  bf16_t* __restrict__ out, long n) {
  long i = ((long)blockIdx.x * 256 + threadIdx.x) * 8;
  if (i >= n) return;
  float4 a = *(const float4*)(in + i);
  float4 b = *(const float4*)(in + i + 4);
  bf16x8 o;
  o[0] = (bf16_t)a.x; o[1] = (bf16_t)a.y; o[2] = (bf16_t)a.z; o[3] = (bf16_t)a.w;
  o[4] = (bf16_t)b.x; o[5] = (bf16_t)b.y; o[6] = (bf16_t)b.z; o[7] = (bf16_t)b.w;
  *(bf16x8*)(out + i) = o;
}

// ---------------- transpose (K,N) f32 -> (N,K) bf16, 32x32 LDS tiles --------------
__global__ __launch_bounds__(256) void k_transpose_bf16(const float* __restrict__ in,
                                                        bf16_t* __restrict__ out,
                                                        int K, int N) {
  __shared__ float t[32][33];
  int k0 = blockIdx.x * 32, n0 = blockIdx.y * 32;
  int tx = threadIdx.x & 31, ty = threadIdx.x >> 5;  // 32 x 8
#pragma unroll
  for (int r = 0; r < 4; ++r)
    t[ty + r * 8][tx] = in[(long)(k0 + ty + r * 8) * N + n0 + tx];
  __syncthreads();
#pragma unroll
  for (int r = 0; r < 4; ++r)
    out[(long)(n0 + ty + r * 8) * K + k0 + tx] = (bf16_t)t[tx][ty + r * 8];
}

// ------- transpose V slice: fp32 [B*S][LD] (pre-offset to V cols) -> bf16 [B*512][S]
__global__ __launch_bounds__(256) void k_transpose_vf(const float* __restrict__ in,
                                                      bf16_t* __restrict__ out,
                                                      int S, int LD) {
  __shared__ float t[32][33];
  int s0 = blockIdx.x * 32, c0 = blockIdx.y * 32, b = blockIdx.z;
  int tx = threadIdx.x & 31, ty = threadIdx.x >> 5;  // 32 x 8
#pragma unroll
  for (int r = 0; r < 4; ++r)
    t[ty + r * 8][tx] = in[(long)(b * S + s0 + ty + r * 8) * LD + c0 + tx];
  __syncthreads();
#pragma unroll
  for (int r = 0; r < 4; ++r)
    out[(long)(b * 512 + c0 + ty + r * 8) * S + s0 + tx] = (bf16_t)t[tx][ty + r * 8];
}

// ---------------- GEMM: C[M,N] = A[M,K] * Bt[N,K]^T  (bf16 MFMA, fp32 acc) --------
// 128x128 tile, BK=32, 4 waves each 64x64. 2-phase double-buffered (T3 minimum):
// one barrier/iter; gload(t+1) overlaps ds_read+MFMA(t); vmcnt drain at next barrier
// happens after a full MFMA phase of latency hiding.
template <typename OUT_T>
__global__ __launch_bounds__(256) void k_gemm_bt(const bf16_t* __restrict__ A,
                                                 const bf16_t* __restrict__ Bt,
                                                 OUT_T* __restrict__ C,
                                                 int M, int N, int K) {
  __shared__ bf16_t Al[2][128 * 32];
  __shared__ bf16_t Bl[2][128 * 32];
  int tid = threadIdx.x;
  int lane = tid & 63, w = tid >> 6;
  int l16 = lane & 15, lg = lane >> 4;
  int m0 = blockIdx.x * 128, n0 = blockIdx.y * 128;
  int wm = (w >> 1) * 64, wn = (w & 1) * 64;

  int row0 = tid >> 2, koff = (tid & 3) * 8;
  const bf16_t* Ag0 = A + (long)(m0 + row0) * K + koff;
  const bf16_t* Ag1 = A + (long)(m0 + row0 + 64) * K + koff;
  const bf16_t* Bg0 = Bt + (long)(n0 + row0) * K + koff;
  const bf16_t* Bg1 = Bt + (long)(n0 + row0 + 64) * K + koff;

  f32x4 acc[4][4] = {};
  int nt = K >> 5;

  // prologue: stage tile 0 into buffer 0
  gload16(Ag0, Al[0] + tid * 8);
  gload16(Ag1, Al[0] + 2048 + tid * 8);
  gload16(Bg0, Bl[0] + tid * 8);
  gload16(Bg1, Bl[0] + 2048 + tid * 8);

  int cur = 0;
  for (int t = 0; t < nt; ++t) {
    __syncthreads();  // drains vmcnt (tile t landed) + lgkm; syncs waves
    if (t + 1 < nt) {
      int k0 = (t + 1) << 5;
      bf16_t* Ald = Al[cur ^ 1] + tid * 8;
      bf16_t* Bld = Bl[cur ^ 1] + tid * 8;
      gload16(Ag0 + k0, Ald);
      gload16(Ag1 + k0, Ald + 2048);
      gload16(Bg0 + k0, Bld);
      gload16(Bg1 + k0, Bld + 2048);
    }
    const bf16_t* Ab = Al[cur];
    const bf16_t* Bb = Bl[cur];
    bf16x8 af[4], bfr[4];
#pragma unroll
    for (int mf = 0; mf < 4; ++mf)
      af[mf] = *(const bf16x8*)(Ab + (wm + mf * 16 + l16) * 32 + lg * 8);
#pragma unroll
    for (int nf = 0; nf < 4; ++nf)
      bfr[nf] = *(const bf16x8*)(Bb + (wn + nf * 16 + l16) * 32 + lg * 8);
#pragma unroll
    for (int mf = 0; mf < 4; ++mf)
#pragma unroll
      for (int nf = 0; nf < 4; ++nf)
        acc[mf][nf] = MFMA(af[mf], bfr[nf], acc[mf][nf]);
    cur ^= 1;
  }

#pragma unroll
  for (int mf = 0; mf < 4; ++mf)
#pragma unroll
    for (int nf = 0; nf < 4; ++nf)
#pragma unroll
      for (int r = 0; r < 4; ++r) {
        int row = m0 + wm + mf * 16 + lg * 4 + r;
        int col = n0 + wn + nf * 16 + l16;
        C[(long)row * N + col] = (OUT_T)acc[mf][nf][r];
      }
}

// ---------------- fused LayerNorm (+optional RoPE), fp32 in -> bf16 out -----------
// LN over C cols of a row whose input stride is LD (supports fused projection output).
template <int C, bool ROPE>
__global__ __launch_bounds__(256) void k_ln_rope(const float* __restrict__ in,
                                                 const float* __restrict__ gw,
                                                 const float* __restrict__ gb,
                                                 const float* __restrict__ fc,
                                                 const float* __restrict__ fs,
                                                 bf16_t* __restrict__ out,
                                                 int smask, int LD) {
  int row = blockIdx.x;
  int tid = threadIdx.x;
  const float* x = in + (long)row * LD;
  float s = 0.f, ss = 0.f;
  for (int i = tid * 4; i < C; i += 1024) {
    float4 v = *(const float4*)(x + i);
    s += v.x + v.y + v.z + v.w;
    ss += v.x * v.x + v.y * v.y + v.z * v.z + v.w * v.w;
  }
#pragma unroll
  for (int msk = 1; msk < 64; msk <<= 1) {
    s += __shfl_xor(s, msk);
    ss += __shfl_xor(ss, msk);
  }
  __shared__ float rs[2][4];
  int w = tid >> 6, lane = tid & 63;
  if (lane == 0) { rs[0][w] = s; rs[1][w] = ss; }
  __syncthreads();
  s = rs[0][0] + rs[0][1] + rs[0][2] + rs[0][3];
  ss = rs[1][0] + rs[1][1] + rs[1][2] + rs[1][3];
  float mean = s * (1.0f / (float)C);
  float inv = rsqrtf(ss * (1.0f / (float)C) - mean * mean + 1e-5f);
  int srow = row & smask;
  for (int i = tid * 4; i < C; i += 1024) {
    float4 v = *(const float4*)(x + i);
    float n0 = (v.x - mean) * inv * gw[i + 0] + gb[i + 0];
    float n1 = (v.y - mean) * inv * gw[i + 1] + gb[i + 1];
    float n2 = (v.z - mean) * inv * gw[i + 2] + gb[i + 2];
    float n3 = (v.w - mean) * inv * gw[i + 3] + gb[i + 3];
    bf16x4 o;
    if (ROPE) {
      int dh = i & 63;
      int f0 = dh >> 1, f1 = f0 + 1;
      float c0 = fc[srow * 32 + f0], s0 = fs[srow * 32 + f0];
      float c1 = fc[srow * 32 + f1], s1 = fs[srow * 32 + f1];
      o[0] = (bf16_t)(n0 * c0 - n1 * s0);
      o[1] = (bf16_t)(n0 * s0 + n1 * c0);
      o[2] = (bf16_t)(n2 * c1 - n3 * s1);
      o[3] = (bf16_t)(n2 * s1 + n3 * c1);
    } else {
      o[0] = (bf16_t)n0; o[1] = (bf16_t)n1; o[2] = (bf16_t)n2; o[3] = (bf16_t)n3;
    }
    *(bf16x4*)(out + (long)row * C + i) = o;
  }
}

// ---------------- fused GQA attention: self (S keys) + gated cross (YL keys) -------
// Fixed-max softmax (M=20, shift-invariant => exact), per-lane partial sums,
// one reduce per phase; async reg-staged prefetch of next K/V tile.
__global__ __launch_bounds__(256) void k_attn(const bf16_t* __restrict__ Q,
                                              const bf16_t* __restrict__ Kx,
                                              const bf16_t* __restrict__ Vxt,
                                              const bf16_t* __restrict__ Ky,
                                              const bf16_t* __restrict__ Vyt,
                                              const float* __restrict__ gate,
                                              bf16_t* __restrict__ out, int S, int YL) {
  __shared__ bf16_t Kl[64 * 72];
  __shared__ bf16_t Vt[64 * 72];
  __shared__ bf16_t Pl[4][16 * 72];

  int tid = threadIdx.x;
  int lane = tid & 63, w = tid >> 6;
  int l16 = lane & 15, lg = lane >> 4;
  int qt = blockIdx.x, h = blockIdx.y, b = blockIdx.z;
  int kv = h >> 2;  // n_rep = 4

  bf16x8 qf[2];
  {
    long qoff = ((long)(b * S + qt * 64 + w * 16 + l16)) * 2048 + h * 64;
    qf[0] = *(const bf16x8*)(Q + qoff + lg * 8);
    qf[1] = *(const bf16x8*)(Q + qoff + 32 + lg * 8);
#pragma unroll
    for (int j = 0; j < 8; ++j) {
      qf[0][j] = (bf16_t)((float)qf[0][j] * 0.125f);
      qf[1][j] = (bf16_t)((float)qf[1][j] * 0.125f);
    }
  }

  int kr0 = tid >> 3, kb0 = tid & 7;

  float res[4][4];
  float tg = tanhf(gate[h]);

  for (int phase = 0; phase < 2; ++phase) {
    const bf16_t* Kg = phase ? (Ky + (long)b * YL * 512 + kv * 64)
                             : (Kx + (long)b * S * 512 + kv * 64);
    const bf16_t* Vg = phase ? (Vyt + (long)(b * 8 + kv) * 64 * YL)
                             : (Vxt + (long)(b * 8 + kv) * 64 * S);
    int Sv = phase ? YL : S;
    int nt = Sv >> 6;

    float lrp[4] = {0.f, 0.f, 0.f, 0.f};
    f32x4 o[4] = {};

    bf16x8 kc0, kc1, vc0, vc1;
    {
      kc0 = *(const bf16x8*)(Kg + kr0 * 512 + kb0 * 8);
      kc1 = *(const bf16x8*)(Kg + (kr0 + 32) * 512 + kb0 * 8);
      vc0 = *(const bf16x8*)(Vg + (long)kr0 * Sv + kb0 * 8);
      vc1 = *(const bf16x8*)(Vg + (long)(kr0 + 32) * Sv + kb0 * 8);
    }

    for (int t = 0; t < nt; ++t) {
      __syncthreads();
      *(bf16x8*)(Kl + kr0 * 72 + kb0 * 8) = kc0;
      *(bf16x8*)(Kl + (kr0 + 32) * 72 + kb0 * 8) = kc1;
      *(bf16x8*)(Vt + kr0 * 72 + kb0 * 8) = vc0;
      *(bf16x8*)(Vt + (kr0 + 32) * 72 + kb0 * 8) = vc1;
      __syncthreads();

      if (t + 1 < nt) {
        const bf16_t* kt = Kg + (long)(t + 1) * 64 * 512;
        const bf16_t* vtp = Vg + (t + 1) * 64;
        kc0 = *(const bf16x8*)(kt + kr0 * 512 + kb0 * 8);
        kc1 = *(const bf16x8*)(kt + (kr0 + 32) * 512 + kb0 * 8);
        vc0 = *(const bf16x8*)(vtp + (long)kr0 * Sv + kb0 * 8);
        vc1 = *(const bf16x8*)(vtp + (long)(kr0 + 32) * Sv + kb0 * 8);
      }

      f32x4 sc[4] = {};
      __builtin_amdgcn_s_setprio(1);
#pragma unroll
      for (int kf = 0; kf < 2; ++kf)
#pragma unroll
        for (int nf = 0; nf < 4; ++nf) {
          bf16x8 kfr = *(const bf16x8*)(Kl + (nf * 16 + l16) * 72 + kf * 32 + lg * 8);
          sc[nf] = MFMA(qf[kf], kfr, sc[nf]);
        }
      __builtin_amdgcn_s_setprio(0);

#pragma unroll
      for (int nf = 0; nf < 4; ++nf)
#pragma unroll
        for (int r = 0; r < 4; ++r) {
          float p = __expf(sc[nf][r] - 20.0f);
          lrp[r] += p;
          Pl[w][(lg * 4 + r) * 72 + nf * 16 + l16] = (bf16_t)p;
        }

      __builtin_amdgcn_s_setprio(1);
#pragma unroll
      for (int kb = 0; kb < 2; ++kb) {
        bf16x8 pa = *(const bf16x8*)(&Pl[w][l16 * 72 + kb * 32 + lg * 8]);
#pragma unroll
        for (int df = 0; df < 4; ++df) {
          bf16x8 vb = *(const bf16x8*)(Vt + (df * 16 + l16) * 72 + kb * 32 + lg * 8);
          o[df] = MFMA(pa, vb, o[df]);
        }
      }
      __builtin_amdgcn_s_setprio(0);
    }

    float inv[4];
#pragma unroll
    for (int r = 0; r < 4; ++r) {
      float s_ = lrp[r];
#pragma unroll
      for (int msk = 1; msk < 16; msk <<= 1) s_ += __shfl_xor(s_, msk);
      inv[r] = 1.0f / s_;
    }
#pragma unroll
    for (int df = 0; df < 4; ++df)
#pragma unroll
      for (int r = 0; r < 4; ++r) {
        float v = o[df][r] * inv[r];
        if (phase == 0) res[df][r] = v;
        else res[df][r] += tg * v;
      }
  }

  long obase = ((long)(b * S + qt * 64 + w * 16 + lg * 4)) * 2048 + h * 64 + l16;
#pragma unroll
  for (int df = 0; df < 4; ++df)
#pragma unroll
    for (int r = 0; r < 4; ++r)
      out[obase + (long)r * 2048 + df * 16] = (bf16_t)res[df][r];
}

// ------------------------------- launch ------------------------------------------
extern "C" void kernel_launch(void* const* d_in, const int* in_sizes, int n_in,
                              void* d_out, int out_size, void* d_ws, size_t ws_size,
                              hipStream_t stream) {
  const float* x    = (const float*)d_in[0];
  const float* fc   = (const float*)d_in[2];
  const float* fs   = (const float*)d_in[3];
  const float* y    = (const float*)d_in[4];
  const float* wq   = (const float*)d_in[6];
  const float* wk   = (const float*)d_in[7];
  const float* wv   = (const float*)d_in[8];
  const float* wky  = (const float*)d_in[9];
  const float* wvy  = (const float*)d_in[10];
  const float* wo   = (const float*)d_in[11];
  const float* gate = (const float*)d_in[12];
  const float* qnw  = (const float*)d_in[13];
  const float* qnb  = (const float*)d_in[14];
  const float* knw  = (const float*)d_in[15];
  const float* knb  = (const float*)d_in[16];
  const float* kynw = (const float*)d_in[17];
  const float* kynb = (const float*)d_in[18];
  float* outp = (float*)d_out;

  constexpr int B = 2, S = 2048, D = 2048, YLv = 256, YD = 1024;
  constexpr int MQ = B * S;    // 4096
  constexpr int MY = B * YLv;  // 512
  constexpr int NQK = 2048;
  constexpr int NKVd = 512;

  char* p = (char*)d_ws;
  auto alloc = [&](long bytes) { char* r = p; p += (bytes + 255) & ~255L; return r; };
  float*  tmp   = (float*)alloc((long)MQ * 3072 * 4);  // fused qkv fp32 out; attb aliases later
  bf16_t* xb    = (bf16_t*)alloc((long)MQ * D * 2);
  bf16_t* yb    = (bf16_t*)alloc((long)MY * YD * 2);
  bf16_t* wqkvt = (bf16_t*)alloc((long)3072 * D * 2);   // [wq|wk|wv]^T rows
  bf16_t* wkvyt = (bf16_t*)alloc((long)1024 * YD * 2);  // [ky|vy]^T rows
  bf16_t* wot   = (bf16_t*)alloc((long)D * NQK * 2);
  bf16_t* Qb    = (bf16_t*)alloc((long)MQ * NQK * 2);
  bf16_t* Kb    = (bf16_t*)alloc((long)MQ * NKVd * 2);
  bf16_t* Vxt   = (bf16_t*)alloc((long)B * NKVd * S * 2);   // [B*512][S]
  bf16_t* yKb   = (bf16_t*)alloc((long)MY * NKVd * 2);
  bf16_t* yVt   = (bf16_t*)alloc((long)B * NKVd * YLv * 2); // [B*512][YL]
  bf16_t* attb  = (bf16_t*)tmp;  // overlay: all tmp reads precede k_attn's write

  // activations -> bf16
  k_cvt_bf16<<<dim3(((long)MQ * D) / 2048), dim3(256), 0, stream>>>(x, xb, (long)MQ * D);
  k_cvt_bf16<<<dim3(((long)MY * YD) / 2048), dim3(256), 0, stream>>>(y, yb, (long)MY * YD);
  // weights -> transposed bf16 (N,K); q/k/v concatenated into one [3072][D]
  k_transpose_bf16<<<dim3(D / 32, NQK / 32), dim3(256), 0, stream>>>(wq, wqkvt, D, NQK);
  k_transpose_bf16<<<dim3(D / 32, NKVd / 32), dim3(256), 0, stream>>>(wk, wqkvt + (long)2048 * D, D, NKVd);
  k_transpose_bf16<<<dim3(D / 32, NKVd / 32), dim3(256), 0, stream>>>(wv, wqkvt + (long)2560 * D, D, NKVd);
  k_transpose_bf16<<<dim3(YD / 32, NKVd / 32), dim3(256), 0, stream>>>(wky, wkvyt, YD, NKVd);
  k_transpose_bf16<<<dim3(YD / 32, NKVd / 32), dim3(256), 0, stream>>>(wvy, wkvyt + (long)512 * YD, YD, NKVd);
  k_transpose_bf16<<<dim3(NQK / 32, D / 32), dim3(256), 0, stream>>>(wo, wot, NQK, D);

  // fused QKV: x@[wq|wk|wv] -> tmp [4096][3072]  (768 wgs = 3 blocks/CU)
  k_gemm_bt<float><<<dim3(MQ / 128, 3072 / 128), dim3(256), 0, stream>>>(xb, wqkvt, tmp, MQ, 3072, D);
  k_ln_rope<2048, true><<<dim3(MQ), dim3(256), 0, stream>>>(tmp, qnw, qnb, fc, fs, Qb, S - 1, 3072);
  k_ln_rope<512, true><<<dim3(MQ), dim3(256), 0, stream>>>(tmp + 2048, knw, knb, fc, fs, Kb, S - 1, 3072);
  k_transpose_vf<<<dim3(S / 32, 16, B), dim3(256), 0, stream>>>(tmp + 2560, Vxt, S, 3072);
  // yKV fused: y@[wky|wvy] -> tmp [512][1024]
  k_gemm_bt<float><<<dim3(MY / 128, 1024 / 128), dim3(256), 0, stream>>>(yb, wkvyt, tmp, MY, 1024, YD);
  k_ln_rope<512, false><<<dim3(MY), dim3(256), 0, stream>>>(tmp, kynw, kynb, fc, fs, yKb, 0, 1024);
  k_transpose_vf<<<dim3(YLv / 32, 16, B), dim3(256), 0, stream>>>(tmp + 512, yVt, YLv, 1024);
  // fused self + gated cross attention
  k_attn<<<dim3(S / 64, 32, B), dim3(256), 0, stream>>>(Qb, Kb, Vxt, yKb, yVt, gate, attb, S, YLv);
  // out = att @ wo
  k_gemm_bt<float><<<dim3(MQ / 128, D / 128), dim3(256), 0, stream>>>(attb, wot, outp, MQ, D, NQK);
}